// Round 3
// baseline (349.613 us; speedup 1.0000x reference)
//
#include <hip/hip_runtime.h>
#include <hip/hip_bf16.h>
#include <math.h>

#define B_SZ    1024
#define DI      2560
#define DS      16
#define DR      160

typedef __bf16 bf16x8 __attribute__((ext_vector_type(8)));
typedef float  f32x4  __attribute__((ext_vector_type(4)));

__device__ __forceinline__ float fast_exp2(float x) {
#if __has_builtin(__builtin_amdgcn_exp2f)
  return __builtin_amdgcn_exp2f(x);   // v_exp_f32
#else
  return exp2f(x);
#endif
}
__device__ __forceinline__ float fast_log2(float x) {
#if __has_builtin(__builtin_amdgcn_logf)
  return __builtin_amdgcn_logf(x);    // v_log_f32
#else
  return log2f(x);
#endif
}

#define LOG2E 1.44269504088896f
#define LN2   0.693147180559945f

// load 8 consecutive fp32 and convert to a bf16x8 MFMA fragment in-register
__device__ __forceinline__ bf16x8 cvt8(const float* __restrict__ p) {
  float4 v0 = *(const float4*)p;
  float4 v1 = *(const float4*)(p + 4);
  bf16x8 r;
  r[0] = (__bf16)v0.x; r[1] = (__bf16)v0.y; r[2] = (__bf16)v0.z; r[3] = (__bf16)v0.w;
  r[4] = (__bf16)v1.x; r[5] = (__bf16)v1.y; r[6] = (__bf16)v1.z; r[7] = (__bf16)v1.w;
  return r;
}

// ---------------- kernel 1: proj GEMM  [1024,192] = x . [Wdl;WB;WC]^T --------
// one wave per 16x16 tile; fp32 operands converted to bf16 in-register.
__global__ void __launch_bounds__(64) proj_kernel(
    const float* __restrict__ x, const float* __restrict__ Wdl,
    const float* __restrict__ WB, const float* __restrict__ WC,
    __bf16* __restrict__ dtlow, float* __restrict__ Bt, float* __restrict__ Ct) {
  int gw    = blockIdx.x;                  // 768 wave-tiles
  int lane  = threadIdx.x;                 // 0..63
  int mtile = gw & 63;                     // 64 m-tiles of 16
  int ntile = gw >> 6;                     // 12 n-tiles of 16
  int b0 = mtile * 16, n0 = ntile * 16;
  int m = lane & 15, quad = lane >> 4;
  int nn = n0 + m;
  const float* ap = x + (size_t)(b0 + m) * DI + quad * 8;
  const float* wrow;
  if (nn < DR)            wrow = Wdl + (size_t)nn * DI;
  else if (nn < DR + DS)  wrow = WB  + (size_t)(nn - DR) * DI;
  else                    wrow = WC  + (size_t)(nn - DR - DS) * DI;
  const float* bp = wrow + quad * 8;

  f32x4 acc = {0.f, 0.f, 0.f, 0.f};
#pragma unroll 4
  for (int k0 = 0; k0 < DI; k0 += 32) {
    bf16x8 a = cvt8(ap + k0);
    bf16x8 b = cvt8(bp + k0);
    acc = __builtin_amdgcn_mfma_f32_16x16x32_bf16(a, b, acc, 0, 0, 0);
  }
  // D layout: col = lane&15 (n), row = quad*4 + r (m)
#pragma unroll
  for (int r = 0; r < 4; ++r) {
    int bb = b0 + quad * 4 + r;
    float v = acc[r];
    if (nn < DR)            dtlow[bb * DR + nn] = (__bf16)v;
    else if (nn < DR + DS)  Bt[bb * DS + (nn - DR)] = v;
    else                    Ct[bb * DS + (nn - DR - DS)] = v;
  }
}

// ---------------- kernel 2: fused dt GEMM + softplus + SSM state pass --------
// per wave: 16x16 (b,d) tile. MFMA gives dt_raw; lane owns 4 (b,d) pairs
// (bb = b0+quad*4+r, dd = d0+(lane&15)) and runs the state update for them.
__global__ void __launch_bounds__(256) dtssm_kernel(
    const __bf16* __restrict__ dtlow, const float* __restrict__ Wdt,
    const float* __restrict__ b_dt, const float* __restrict__ x,
    const float* __restrict__ h, const float* __restrict__ A_log,
    const float* __restrict__ Bt, const float* __restrict__ Ct,
    const float* __restrict__ Dp, float* __restrict__ y) {
  int gw    = blockIdx.x * 4 + (threadIdx.x >> 6);   // 10240 wave-tiles
  int lane  = threadIdx.x & 63;
  int mtile = gw & 63;       // 64 b-tiles
  int ntile = gw >> 6;       // 160 d-tiles
  int b0 = mtile * 16, d0 = ntile * 16;
  int m = lane & 15, quad = lane >> 4;
  int dd = d0 + m;

  // --- dt GEMM: K=160 in 5 MFMA steps; W_dt fp32 -> bf16 in-register
  const __bf16* ap = dtlow + (size_t)(b0 + m) * DR + quad * 8;
  const float*  bp = Wdt   + (size_t)dd * DR + quad * 8;
  f32x4 acc = {0.f, 0.f, 0.f, 0.f};
#pragma unroll
  for (int k0 = 0; k0 < DR; k0 += 32) {
    bf16x8 a = *(const bf16x8*)(ap + k0);
    bf16x8 b = cvt8(bp + k0);
    acc = __builtin_amdgcn_mfma_f32_16x16x32_bf16(a, b, acc, 0, 0, 0);
  }

  float bias = b_dt[dd];
  float dv   = Dp[dd];
  // negA2 = -exp(A_log)*log2e computed in-register (row depends only on dd)
  const float4* al4 = (const float4*)(A_log + (size_t)dd * DS);
  float4 av0, av1, av2, av3;
  {
    float4 l0 = al4[0], l1 = al4[1], l2 = al4[2], l3 = al4[3];
    av0.x = -fast_exp2(l0.x * LOG2E) * LOG2E; av0.y = -fast_exp2(l0.y * LOG2E) * LOG2E;
    av0.z = -fast_exp2(l0.z * LOG2E) * LOG2E; av0.w = -fast_exp2(l0.w * LOG2E) * LOG2E;
    av1.x = -fast_exp2(l1.x * LOG2E) * LOG2E; av1.y = -fast_exp2(l1.y * LOG2E) * LOG2E;
    av1.z = -fast_exp2(l1.z * LOG2E) * LOG2E; av1.w = -fast_exp2(l1.w * LOG2E) * LOG2E;
    av2.x = -fast_exp2(l2.x * LOG2E) * LOG2E; av2.y = -fast_exp2(l2.y * LOG2E) * LOG2E;
    av2.z = -fast_exp2(l2.z * LOG2E) * LOG2E; av2.w = -fast_exp2(l2.w * LOG2E) * LOG2E;
    av3.x = -fast_exp2(l3.x * LOG2E) * LOG2E; av3.y = -fast_exp2(l3.y * LOG2E) * LOG2E;
    av3.z = -fast_exp2(l3.z * LOG2E) * LOG2E; av3.w = -fast_exp2(l3.w * LOG2E) * LOG2E;
  }

#pragma unroll
  for (int r = 0; r < 4; ++r) {
    int bb = b0 + quad * 4 + r;
    // softplus(z) = log2(1 + 2^(z*log2e)) * ln2
    float z = acc[r] + bias;
    float t = fast_exp2(z * LOG2E);
    float dt = (z > 80.f) ? z : fast_log2(1.f + t) * LN2;

    size_t e = (size_t)bb * DI + dd;
    float xv  = x[e];
    float dxv = dt * xv;
    const float4* h4 = (const float4*)(h  + e * DS);
    const float4* b4 = (const float4*)(Bt + (size_t)bb * DS);
    const float4* c4 = (const float4*)(Ct + (size_t)bb * DS);
    float s = 0.f;
#pragma unroll
    for (int j = 0; j < 4; ++j) {
      float4 hv = h4[j], bv = b4[j], cv = c4[j];
      float4 avj = (j == 0) ? av0 : (j == 1) ? av1 : (j == 2) ? av2 : av3;
      s += (fast_exp2(avj.x * dt) * hv.x + bv.x * dxv) * cv.x;
      s += (fast_exp2(avj.y * dt) * hv.y + bv.y * dxv) * cv.y;
      s += (fast_exp2(avj.z * dt) * hv.z + bv.z * dxv) * cv.z;
      s += (fast_exp2(avj.w * dt) * hv.w + bv.w * dxv) * cv.w;
    }
    y[e] = s + dv * xv;
  }
}

extern "C" void kernel_launch(void* const* d_in, const int* in_sizes, int n_in,
                              void* d_out, int out_size, void* d_ws, size_t ws_size,
                              hipStream_t stream) {
  const float* x     = (const float*)d_in[0];
  const float* h     = (const float*)d_in[1];
  const float* Wdl   = (const float*)d_in[2];
  const float* Wdt   = (const float*)d_in[3];
  const float* b_dt  = (const float*)d_in[4];
  const float* WB    = (const float*)d_in[5];
  const float* WC    = (const float*)d_in[6];
  const float* A_log = (const float*)d_in[7];
  const float* Dp    = (const float*)d_in[8];
  float* y = (float*)d_out;

  // workspace: dtlow bf16 [1024,160], Bt/Ct fp32 [1024,16]
  char* ws = (char*)d_ws;
  __bf16* dtlow = (__bf16*)(ws);               // 327,680 B
  float*  Bt    = (float*) (ws + 327680);      //  65,536 B
  float*  Ct    = (float*) (ws + 393216);      //  65,536 B -> 458,752 total
  if (ws_size < 458752) return;

  // k1: 768 one-wave blocks (spread over all CUs), fp32->bf16 in-register
  proj_kernel<<<768, 64, 0, stream>>>(x, Wdl, WB, WC, dtlow, Bt, Ct);
  // k2: fused dt GEMM + softplus + ssm. 10240 wave-tiles / 4 per block
  dtssm_kernel<<<2560, 256, 0, stream>>>(dtlow, Wdt, b_dt, x, h, A_log,
                                         Bt, Ct, Dp, y);
}

// Round 5
// 333.221 us; speedup vs baseline: 1.0492x; 1.0492x over previous
//
#include <hip/hip_runtime.h>
#include <hip/hip_bf16.h>
#include <math.h>

#define B_SZ    1024
#define DI      2560
#define DS      16
#define DR      160

typedef __bf16 bf16x8 __attribute__((ext_vector_type(8)));
typedef float  f32x4  __attribute__((ext_vector_type(4)));

__device__ __forceinline__ float fast_exp2(float x) {
#if __has_builtin(__builtin_amdgcn_exp2f)
  return __builtin_amdgcn_exp2f(x);   // v_exp_f32
#else
  return exp2f(x);
#endif
}
__device__ __forceinline__ float fast_log2(float x) {
#if __has_builtin(__builtin_amdgcn_logf)
  return __builtin_amdgcn_logf(x);    // v_log_f32
#else
  return log2f(x);
#endif
}

#define LOG2E 1.44269504088896f
#define LN2   0.693147180559945f

// ---------------- kernel 0: vectorized fp32->bf16 + negA2 = -exp(A_log)*log2e
// 8 elements per thread. Group counts (x8 elems):
//   xb 327680 | wcat(Wdl) 51200 | wcat(WB) 5120 | wcat(WC) 5120 |
//   wdtb 51200 | negA2 5120   -> total 445440 groups = 1740 blocks x 256
__global__ void __launch_bounds__(256) convert_kernel(
    const float* __restrict__ x, const float* __restrict__ Wdl,
    const float* __restrict__ WB, const float* __restrict__ WC,
    const float* __restrict__ Wdt, const float* __restrict__ A_log,
    __bf16* __restrict__ xb, __bf16* __restrict__ wcat,
    __bf16* __restrict__ wdtb, float* __restrict__ negA2) {
  int g = blockIdx.x * 256 + threadIdx.x;
  const int GX = 327680, GWDL = 51200, GWB = 5120, GWDT = 51200;
  const float* src;
  __bf16* dst;
  if (g < GX) { src = x; dst = xb; }
  else if ((g -= GX) < GWDL) { src = Wdl; dst = wcat; }
  else if ((g -= GWDL) < GWB) { src = WB; dst = wcat + DR * DI; }
  else if ((g -= GWB) < GWB) { src = WC; dst = wcat + (DR + DS) * DI; }
  else if ((g -= GWB) < GWDT) { src = Wdt; dst = wdtb; }
  else {
    g -= GWDT;   // negA2 region: 8 floats in, 8 floats out
    const f32x4* s = (const f32x4*)A_log + (size_t)g * 2;
    f32x4 a = s[0], b = s[1], o0, o1;
    o0.x = -fast_exp2(a.x * LOG2E) * LOG2E; o0.y = -fast_exp2(a.y * LOG2E) * LOG2E;
    o0.z = -fast_exp2(a.z * LOG2E) * LOG2E; o0.w = -fast_exp2(a.w * LOG2E) * LOG2E;
    o1.x = -fast_exp2(b.x * LOG2E) * LOG2E; o1.y = -fast_exp2(b.y * LOG2E) * LOG2E;
    o1.z = -fast_exp2(b.z * LOG2E) * LOG2E; o1.w = -fast_exp2(b.w * LOG2E) * LOG2E;
    f32x4* d = (f32x4*)negA2 + (size_t)g * 2;
    d[0] = o0; d[1] = o1;
    return;
  }
  f32x4 v0 = ((const f32x4*)src)[(size_t)g * 2];
  f32x4 v1 = ((const f32x4*)src)[(size_t)g * 2 + 1];
  bf16x8 r;
  r[0] = (__bf16)v0.x; r[1] = (__bf16)v0.y; r[2] = (__bf16)v0.z; r[3] = (__bf16)v0.w;
  r[4] = (__bf16)v1.x; r[5] = (__bf16)v1.y; r[6] = (__bf16)v1.z; r[7] = (__bf16)v1.w;
  *(bf16x8*)(dst + (size_t)g * 8) = r;
}

// ---------------- kernel 1: proj GEMM  C[1024,192] = xb . wcat^T -------------
// one wave per 16x16 tile, K=2560 in 80 MFMA steps; 768 blocks x 64 thr
__global__ void __launch_bounds__(64) proj_kernel(
    const __bf16* __restrict__ xb, const __bf16* __restrict__ wcat,
    __bf16* __restrict__ dtlow, float* __restrict__ Bt, float* __restrict__ Ct) {
  int gw    = blockIdx.x;                  // 768 wave-tiles
  int lane  = threadIdx.x;                 // 0..63
  int mtile = gw & 63;                     // 64 m-tiles of 16
  int ntile = gw >> 6;                     // 12 n-tiles of 16
  int b0 = mtile * 16, n0 = ntile * 16;
  int m = lane & 15, quad = lane >> 4;
  const __bf16* ap = xb   + (size_t)(b0 + m) * DI + quad * 8;
  const __bf16* bp = wcat + (size_t)(n0 + m) * DI + quad * 8;
  f32x4 acc = {0.f, 0.f, 0.f, 0.f};
#pragma unroll 4
  for (int k0 = 0; k0 < DI; k0 += 32) {
    bf16x8 a = *(const bf16x8*)(ap + k0);
    bf16x8 b = *(const bf16x8*)(bp + k0);
    acc = __builtin_amdgcn_mfma_f32_16x16x32_bf16(a, b, acc, 0, 0, 0);
  }
  // D layout: col = lane&15 (n), row = quad*4 + r (m)
  int nn = n0 + m;
#pragma unroll
  for (int r = 0; r < 4; ++r) {
    int bb = b0 + quad * 4 + r;
    float v = acc[r];
    if (nn < DR)            dtlow[bb * DR + nn] = (__bf16)v;
    else if (nn < DR + DS)  Bt[bb * DS + (nn - DR)] = v;
    else                    Ct[bb * DS + (nn - DR - DS)] = v;
  }
}

// ---------------- kernel 2: fused dt GEMM + softplus + SSM state pass --------
// per wave: 16x16 (b,d) tile. MFMA gives dt_raw; lane owns 4 (b,d) pairs
// (bb = b0+quad*4+r, dd = d0+(lane&15)) and runs the state update for them.
__global__ void __launch_bounds__(256) dtssm_kernel(
    const __bf16* __restrict__ dtlow, const __bf16* __restrict__ wdtb,
    const float* __restrict__ b_dt, const float* __restrict__ x,
    const float* __restrict__ h, const float* __restrict__ negA2,
    const float* __restrict__ Bt, const float* __restrict__ Ct,
    const float* __restrict__ Dp, float* __restrict__ y) {
  int gw    = blockIdx.x * 4 + (threadIdx.x >> 6);   // 10240 wave-tiles
  int lane  = threadIdx.x & 63;
  int mtile = gw & 63;       // 64 b-tiles
  int ntile = gw >> 6;       // 160 d-tiles
  int b0 = mtile * 16, d0 = ntile * 16;
  int m = lane & 15, quad = lane >> 4;
  int dd = d0 + m;

  // --- dt GEMM: K=160 in 5 MFMA steps (bf16 staged operands)
  const __bf16* ap = dtlow + (size_t)(b0 + m) * DR + quad * 8;
  const __bf16* bp = wdtb  + (size_t)dd * DR + quad * 8;
  f32x4 acc = {0.f, 0.f, 0.f, 0.f};
#pragma unroll
  for (int k0 = 0; k0 < DR; k0 += 32) {
    bf16x8 a = *(const bf16x8*)(ap + k0);
    bf16x8 b = *(const bf16x8*)(bp + k0);
    acc = __builtin_amdgcn_mfma_f32_16x16x32_bf16(a, b, acc, 0, 0, 0);
  }

  float bias = b_dt[dd];
  float dv   = Dp[dd];
  // negA2 row depends only on dd: load once (log2e pre-folded)
  const f32x4* a4 = (const f32x4*)(negA2 + (size_t)dd * DS);
  f32x4 av0 = a4[0], av1 = a4[1], av2 = a4[2], av3 = a4[3];

#pragma unroll
  for (int r = 0; r < 4; ++r) {
    int bb = b0 + quad * 4 + r;
    // softplus(z) = log2(1 + 2^(z*log2e)) * ln2
    float z = acc[r] + bias;
    float t = fast_exp2(z * LOG2E);
    float dt = (z > 80.f) ? z : fast_log2(1.f + t) * LN2;

    size_t e = (size_t)bb * DI + dd;
    float xv  = x[e];
    float dxv = dt * xv;
    const f32x4* h4 = (const f32x4*)(h  + e * DS);
    const f32x4* b4 = (const f32x4*)(Bt + (size_t)bb * DS);
    const f32x4* c4 = (const f32x4*)(Ct + (size_t)bb * DS);
    float s = 0.f;
#pragma unroll
    for (int j = 0; j < 4; ++j) {
      f32x4 hv = __builtin_nontemporal_load(h4 + j);   // h: 168MB read-once
      f32x4 bv = b4[j], cv = c4[j];
      f32x4 avj = (j == 0) ? av0 : (j == 1) ? av1 : (j == 2) ? av2 : av3;
      s += (fast_exp2(avj.x * dt) * hv.x + bv.x * dxv) * cv.x;
      s += (fast_exp2(avj.y * dt) * hv.y + bv.y * dxv) * cv.y;
      s += (fast_exp2(avj.z * dt) * hv.z + bv.z * dxv) * cv.z;
      s += (fast_exp2(avj.w * dt) * hv.w + bv.w * dxv) * cv.w;
    }
    __builtin_nontemporal_store(s + dv * xv, y + e);    // y: write-once
  }
}

extern "C" void kernel_launch(void* const* d_in, const int* in_sizes, int n_in,
                              void* d_out, int out_size, void* d_ws, size_t ws_size,
                              hipStream_t stream) {
  const float* x     = (const float*)d_in[0];
  const float* h     = (const float*)d_in[1];
  const float* Wdl   = (const float*)d_in[2];
  const float* Wdt   = (const float*)d_in[3];
  const float* b_dt  = (const float*)d_in[4];
  const float* WB    = (const float*)d_in[5];
  const float* WC    = (const float*)d_in[6];
  const float* A_log = (const float*)d_in[7];
  const float* Dp    = (const float*)d_in[8];
  float* y = (float*)d_out;

  // workspace layout (256B-aligned offsets)
  char* ws = (char*)d_ws;
  __bf16* xb    = (__bf16*)(ws);                       // 5,242,880 B
  __bf16* wcat  = (__bf16*)(ws + 5242880);             //   983,040 B
  __bf16* wdtb  = (__bf16*)(ws + 6225920);             //   819,200 B
  float*  negA2 = (float*) (ws + 7045120);             //   163,840 B
  __bf16* dtlow = (__bf16*)(ws + 7208960);             //   327,680 B
  float*  Bt    = (float*) (ws + 7536640);             //    65,536 B
  float*  Ct    = (float*) (ws + 7602176);             //    65,536 B -> 7,667,712 total
  if (ws_size < 7667712) return;

  // k0: vectorized conversions, 445440 groups of 8 elems
  convert_kernel<<<1740, 256, 0, stream>>>(x, Wdl, WB, WC, Wdt, A_log,
                                           xb, wcat, wdtb, negA2);
  // k1: 768 one-wave blocks (spread over all CUs)
  proj_kernel<<<768, 64, 0, stream>>>(xb, wcat, dtlow, Bt, Ct);
  // k2: fused dt GEMM + softplus + ssm. 10240 wave-tiles / 4 per block
  dtssm_kernel<<<2560, 256, 0, stream>>>(dtlow, wdtb, b_dt, x, h, negA2,
                                         Bt, Ct, Dp, y);
}

// Round 6
// 320.679 us; speedup vs baseline: 1.0902x; 1.0391x over previous
//
#include <hip/hip_runtime.h>
#include <hip/hip_bf16.h>
#include <math.h>

#define B_SZ    1024
#define DI      2560
#define DS      16
#define DR      160

typedef __bf16 bf16x8 __attribute__((ext_vector_type(8)));
typedef float  f32x4  __attribute__((ext_vector_type(4)));

__device__ __forceinline__ float fast_exp2(float x) {
#if __has_builtin(__builtin_amdgcn_exp2f)
  return __builtin_amdgcn_exp2f(x);   // v_exp_f32
#else
  return exp2f(x);
#endif
}
__device__ __forceinline__ float fast_log2(float x) {
#if __has_builtin(__builtin_amdgcn_logf)
  return __builtin_amdgcn_logf(x);    // v_log_f32
#else
  return log2f(x);
#endif
}

#define LOG2E 1.44269504088896f
#define LN2   0.693147180559945f

// ---------------- kernel 0: vectorized fp32->bf16 + negA2 = -exp(A_log)*log2e
__global__ void __launch_bounds__(256) convert_kernel(
    const float* __restrict__ x, const float* __restrict__ Wdl,
    const float* __restrict__ WB, const float* __restrict__ WC,
    const float* __restrict__ Wdt, const float* __restrict__ A_log,
    __bf16* __restrict__ xb, __bf16* __restrict__ wcat,
    __bf16* __restrict__ wdtb, float* __restrict__ negA2) {
  int g = blockIdx.x * 256 + threadIdx.x;
  const int GX = 327680, GWDL = 51200, GWB = 5120, GWDT = 51200;
  const float* src;
  __bf16* dst;
  if (g < GX) { src = x; dst = xb; }
  else if ((g -= GX) < GWDL) { src = Wdl; dst = wcat; }
  else if ((g -= GWDL) < GWB) { src = WB; dst = wcat + DR * DI; }
  else if ((g -= GWB) < GWB) { src = WC; dst = wcat + (DR + DS) * DI; }
  else if ((g -= GWB) < GWDT) { src = Wdt; dst = wdtb; }
  else {
    g -= GWDT;   // negA2 region: 8 floats in, 8 floats out
    const f32x4* s = (const f32x4*)A_log + (size_t)g * 2;
    f32x4 a = s[0], b = s[1], o0, o1;
    o0.x = -fast_exp2(a.x * LOG2E) * LOG2E; o0.y = -fast_exp2(a.y * LOG2E) * LOG2E;
    o0.z = -fast_exp2(a.z * LOG2E) * LOG2E; o0.w = -fast_exp2(a.w * LOG2E) * LOG2E;
    o1.x = -fast_exp2(b.x * LOG2E) * LOG2E; o1.y = -fast_exp2(b.y * LOG2E) * LOG2E;
    o1.z = -fast_exp2(b.z * LOG2E) * LOG2E; o1.w = -fast_exp2(b.w * LOG2E) * LOG2E;
    f32x4* d = (f32x4*)negA2 + (size_t)g * 2;
    d[0] = o0; d[1] = o1;
    return;
  }
  f32x4 v0 = ((const f32x4*)src)[(size_t)g * 2];
  f32x4 v1 = ((const f32x4*)src)[(size_t)g * 2 + 1];
  bf16x8 r;
  r[0] = (__bf16)v0.x; r[1] = (__bf16)v0.y; r[2] = (__bf16)v0.z; r[3] = (__bf16)v0.w;
  r[4] = (__bf16)v1.x; r[5] = (__bf16)v1.y; r[6] = (__bf16)v1.z; r[7] = (__bf16)v1.w;
  *(bf16x8*)(dst + (size_t)g * 8) = r;
}

// ---------------- kernel 1: proj GEMM  C[1024,192] = xb . wcat^T -------------
__global__ void __launch_bounds__(64) proj_kernel(
    const __bf16* __restrict__ xb, const __bf16* __restrict__ wcat,
    __bf16* __restrict__ dtlow, float* __restrict__ Bt, float* __restrict__ Ct) {
  int gw    = blockIdx.x;                  // 768 wave-tiles
  int lane  = threadIdx.x;                 // 0..63
  int mtile = gw & 63;                     // 64 m-tiles of 16
  int ntile = gw >> 6;                     // 12 n-tiles of 16
  int b0 = mtile * 16, n0 = ntile * 16;
  int m = lane & 15, quad = lane >> 4;
  const __bf16* ap = xb   + (size_t)(b0 + m) * DI + quad * 8;
  const __bf16* bp = wcat + (size_t)(n0 + m) * DI + quad * 8;
  f32x4 acc = {0.f, 0.f, 0.f, 0.f};
#pragma unroll 4
  for (int k0 = 0; k0 < DI; k0 += 32) {
    bf16x8 a = *(const bf16x8*)(ap + k0);
    bf16x8 b = *(const bf16x8*)(bp + k0);
    acc = __builtin_amdgcn_mfma_f32_16x16x32_bf16(a, b, acc, 0, 0, 0);
  }
  // D layout: col = lane&15 (n), row = quad*4 + r (m)
  int nn = n0 + m;
#pragma unroll
  for (int r = 0; r < 4; ++r) {
    int bb = b0 + quad * 4 + r;
    float v = acc[r];
    if (nn < DR)            dtlow[bb * DR + nn] = (__bf16)v;
    else if (nn < DR + DS)  Bt[bb * DS + (nn - DR)] = v;
    else                    Ct[bb * DS + (nn - DR - DS)] = v;
  }
}

// ---------------- kernel 2: fused dt GEMM + softplus + SSM state pass --------
// per wave: 16x16 (b,d) tile; lane owns 4 (b,d) pairs (bb=b0+quad*4+r,
// dd=d0+(lane&15)). All 16 h-loads prefetched into registers before use.
__global__ void __launch_bounds__(256, 3) dtssm_kernel(
    const __bf16* __restrict__ dtlow, const __bf16* __restrict__ wdtb,
    const float* __restrict__ b_dt, const float* __restrict__ x,
    const float* __restrict__ h, const float* __restrict__ negA2,
    const float* __restrict__ Bt, const float* __restrict__ Ct,
    const float* __restrict__ Dp, float* __restrict__ y) {
  int gw    = blockIdx.x * 4 + (threadIdx.x >> 6);   // 10240 wave-tiles
  int lane  = threadIdx.x & 63;
  int mtile = gw & 63;       // 64 b-tiles
  int ntile = gw >> 6;       // 160 d-tiles
  int b0 = mtile * 16, d0 = ntile * 16;
  int m = lane & 15, quad = lane >> 4;
  int dd = d0 + m;

  // --- dt GEMM: K=160 in 5 MFMA steps (bf16 staged operands)
  const __bf16* ap = dtlow + (size_t)(b0 + m) * DR + quad * 8;
  const __bf16* bp = wdtb  + (size_t)dd * DR + quad * 8;
  f32x4 acc = {0.f, 0.f, 0.f, 0.f};
#pragma unroll
  for (int k0 = 0; k0 < DR; k0 += 32) {
    bf16x8 a = *(const bf16x8*)(ap + k0);
    bf16x8 b = *(const bf16x8*)(bp + k0);
    acc = __builtin_amdgcn_mfma_f32_16x16x32_bf16(a, b, acc, 0, 0, 0);
  }

  float bias = b_dt[dd];
  float dv   = Dp[dd];

  // --- softplus for all 4 rows first (frees acc, no mem dependence)
  float dtv[4];
#pragma unroll
  for (int r = 0; r < 4; ++r) {
    float z = acc[r] + bias;
    float t = fast_exp2(z * LOG2E);
    dtv[r] = (z > 80.f) ? z : fast_log2(1.f + t) * LN2;
  }

  // --- prefetch: all 16 h dwordx4 loads + 4 x loads issued before any use
  size_t e0 = (size_t)(b0 + quad * 4) * DI + dd;   // r stride = DI
  f32x4 hb[16];
  float xv[4];
#pragma unroll
  for (int r = 0; r < 4; ++r) {
    const f32x4* h4 = (const f32x4*)(h + (e0 + (size_t)r * DI) * DS);
#pragma unroll
    for (int j = 0; j < 4; ++j)
      hb[r * 4 + j] = __builtin_nontemporal_load(h4 + j);
    xv[r] = x[e0 + (size_t)r * DI];
  }

  // negA2 row depends only on dd (log2e pre-folded)
  const f32x4* a4 = (const f32x4*)(negA2 + (size_t)dd * DS);
  f32x4 av[4];
#pragma unroll
  for (int j = 0; j < 4; ++j) av[j] = a4[j];

#pragma unroll
  for (int r = 0; r < 4; ++r) {
    int bb = b0 + quad * 4 + r;
    float dt  = dtv[r];
    float dxv = dt * xv[r];
    const f32x4* b4 = (const f32x4*)(Bt + (size_t)bb * DS);
    const f32x4* c4 = (const f32x4*)(Ct + (size_t)bb * DS);
    float s = 0.f;
#pragma unroll
    for (int j = 0; j < 4; ++j) {
      f32x4 hv = hb[r * 4 + j];
      f32x4 bv = b4[j], cv = c4[j];
      f32x4 avj = av[j];
      s += (fast_exp2(avj.x * dt) * hv.x + bv.x * dxv) * cv.x;
      s += (fast_exp2(avj.y * dt) * hv.y + bv.y * dxv) * cv.y;
      s += (fast_exp2(avj.z * dt) * hv.z + bv.z * dxv) * cv.z;
      s += (fast_exp2(avj.w * dt) * hv.w + bv.w * dxv) * cv.w;
    }
    __builtin_nontemporal_store(s + dv * xv[r], y + e0 + (size_t)r * DI);
  }
}

extern "C" void kernel_launch(void* const* d_in, const int* in_sizes, int n_in,
                              void* d_out, int out_size, void* d_ws, size_t ws_size,
                              hipStream_t stream) {
  const float* x     = (const float*)d_in[0];
  const float* h     = (const float*)d_in[1];
  const float* Wdl   = (const float*)d_in[2];
  const float* Wdt   = (const float*)d_in[3];
  const float* b_dt  = (const float*)d_in[4];
  const float* WB    = (const float*)d_in[5];
  const float* WC    = (const float*)d_in[6];
  const float* A_log = (const float*)d_in[7];
  const float* Dp    = (const float*)d_in[8];
  float* y = (float*)d_out;

  // workspace layout (256B-aligned offsets)
  char* ws = (char*)d_ws;
  __bf16* xb    = (__bf16*)(ws);                       // 5,242,880 B
  __bf16* wcat  = (__bf16*)(ws + 5242880);             //   983,040 B
  __bf16* wdtb  = (__bf16*)(ws + 6225920);             //   819,200 B
  float*  negA2 = (float*) (ws + 7045120);             //   163,840 B
  __bf16* dtlow = (__bf16*)(ws + 7208960);             //   327,680 B
  float*  Bt    = (float*) (ws + 7536640);             //    65,536 B
  float*  Ct    = (float*) (ws + 7602176);             //    65,536 B -> 7,667,712 total
  if (ws_size < 7667712) return;

  // k0: vectorized conversions, 445440 groups of 8 elems
  convert_kernel<<<1740, 256, 0, stream>>>(x, Wdl, WB, WC, Wdt, A_log,
                                           xb, wcat, wdtb, negA2);
  // k1: 768 one-wave blocks (spread over all CUs)
  proj_kernel<<<768, 64, 0, stream>>>(xb, wcat, dtlow, Bt, Ct);
  // k2: fused dt GEMM + softplus + ssm. 10240 wave-tiles / 4 per block
  dtssm_kernel<<<2560, 256, 0, stream>>>(dtlow, wdtb, b_dt, x, h, negA2,
                                         Bt, Ct, Dp, y);
}